// Round 6
// baseline (215.196 us; speedup 1.0000x reference)
//
#include <hip/hip_runtime.h>

#define BB 8
#define CC 8
#define HH 512
#define WW 512
#define HWSZ (HH * WW)
#define CHW (CC * HWSZ)
#define RPB 8                      // rows per block

typedef float v4 __attribute__((ext_vector_type(4)));

#define LOG2_CLAMP -144.26950409f  // -100 / ln2

__device__ __forceinline__ float sigf(float x) {
    return __builtin_amdgcn_rcpf(1.0f + __expf(-x));
}

// Stage 16 shared rows (8 per branch) of global row grow into Lbuf via
// direct-to-LDS async copy. Wave `wave` stages rows 2w,2w+1; each row
// (512 floats) = 2 glds of 64 lanes x 16 B.
// Row map (rr = row&7): rr0,1 = ch3,4 @ h ; rr2,3,4 = ch5,6,7 @ hm ;
//                       rr5,6,7 = ch0,1,2 @ hp. Branch = row>>3.
__device__ __forceinline__ void stage_glds(
    const float* __restrict__ ab, const float* __restrict__ db,
    float* __restrict__ Lbuf, int h, int hm, int hp, int wave, int lane)
{
#pragma unroll
    for (int j = 0; j < 2; ++j) {
        const int row = 2 * wave + j;         // 0..15, wave-uniform
        const int rr  = row & 7;
        const int ch  = (rr < 5) ? rr + 3 : rr - 5;
        const int gr  = (rr < 2) ? h : ((rr < 5) ? hm : hp);
        const float* gbase = ((row < 8) ? ab : db) + ch * HWSZ + gr * WW;
#pragma unroll
        for (int k = 0; k < 2; ++k) {
            const float* g = gbase + k * 256 + lane * 4;     // 16 B / lane
            float* l = Lbuf + row * WW + k * 256;            // uniform base
            __builtin_amdgcn_global_load_lds(
                (const __attribute__((address_space(1))) unsigned int*)g,
                (__attribute__((address_space(3))) unsigned int*)l,
                16, 0, 0);
        }
    }
}

// One branch. Lb = this branch's 8 staged rows. cr6 = raw centers
// ch{0,1,2,5,6,7} (registers); centers ch3,ch4 come from LDS rows 0,1.
template <bool NEED_MIN>
__device__ __forceinline__ void eval_branch(
    const float* __restrict__ Lb, const float* __restrict__ cr6,
    int w, int wl, int wr, float mh0, float mh1, float mw0, float mw1,
    const float* __restrict__ cv,
    float& glo, float& vmin, float& Lbic, float& Lcon)
{
    float s[8];
    s[0] = sigf(cr6[0]); s[1] = sigf(cr6[1]); s[2] = sigf(cr6[2]);
    s[3] = sigf(Lb[0 * WW + w]);
    s[4] = sigf(Lb[1 * WW + w]);
    s[5] = sigf(cr6[3]); s[6] = sigf(cr6[4]); s[7] = sigf(cr6[5]);

    float n[8];
    n[0] = sigf(Lb[4 * WW + wl]) * (mh0 * mw0);   // ch7 @ h-1, w-1
    n[1] = sigf(Lb[3 * WW + w ]) *  mh0;          // ch6 @ h-1, w
    n[2] = sigf(Lb[2 * WW + wr]) * (mh0 * mw1);   // ch5 @ h-1, w+1
    n[3] = sigf(Lb[1 * WW + wl]) *  mw0;          // ch4 @ h,   w-1
    n[4] = sigf(Lb[0 * WW + wr]) *  mw1;          // ch3 @ h,   w+1
    n[5] = sigf(Lb[7 * WW + wl]) * (mh1 * mw0);   // ch2 @ h+1, w-1
    n[6] = sigf(Lb[6 * WW + w ]) *  mh1;          // ch1 @ h+1, w
    n[7] = sigf(Lb[5 * WW + wr]) * (mh1 * mw1);   // ch0 @ h+1, w+1

    float pb0 = 1.f, pb1 = 1.f, pc = 1.f, vsum = 0.f;
    if (NEED_MIN) vmin = 1e30f;
#pragma unroll
    for (int k = 0; k < 8; ++k) {
        float v = s[k] * n[k];
        vsum += v;
        if (NEED_MIN) vmin = fminf(vmin, v);
        float t  = cv[k];
        float av = (t > 0.5f) ? v    : 1.0f - v;
        float as = (t > 0.5f) ? s[k] : 1.0f - s[k];
        if (k < 4) pb0 *= av; else pb1 *= av;
        pc *= as;
    }
    glo  = vsum * 0.125f;
    Lbic = fmaxf(__log2f(pb0), LOG2_CLAMP) + fmaxf(__log2f(pb1), LOG2_CLAMP);
    Lcon = fmaxf(__log2f(pc), LOG2_CLAMP);
}

__global__ __launch_bounds__(512, 4) void bicon_loss_kernel(
    const float* __restrict__ atts, const float* __restrict__ dets,
    const float* __restrict__ target, const float* __restrict__ con,
    float* __restrict__ out)
{
    __shared__ float L[2][16 * WW];   // 2 x 32 KB double buffer
    __shared__ float wsum[8];

    const int t    = threadIdx.x;     // = w
    const int lane = t & 63;
    const int wave = t >> 6;
    const int w    = t;

    const int   wl  = (w > 0)      ? w - 1 : 0;
    const int   wr  = (w < WW - 1) ? w + 1 : WW - 1;
    const float mw0 = (w > 0)      ? 1.0f : 0.0f;
    const float mw1 = (w < WW - 1) ? 1.0f : 0.0f;

    const int row0 = blockIdx.x * RPB;   // global row (b*H + h); RPB | HH so
                                         // a block never crosses a batch b

    // ---------------- prologue: issue everything for row 0 ----------------
    {
        const int h  = row0 & (HH - 1);
        const int b  = row0 >> 9;
        const int hm = (h > 0) ? h - 1 : 0;
        const int hp = (h < HH - 1) ? h + 1 : HH - 1;
        stage_glds(atts + b * CHW, dets + b * CHW, L[0], h, hm, hp, wave, lane);
    }
    float pfA[6], pfD[6], pfC[8], pfT;
    {
        const int h = row0 & (HH - 1);
        const int b = row0 >> 9;
        const int off = h * WW + w;
        const float* __restrict__ ab = atts + b * CHW + off;
        const float* __restrict__ db = dets + b * CHW + off;
        const float* __restrict__ cb = con  + b * CHW + off;
        const int chn[6] = {0, 1, 2, 5, 6, 7};
#pragma unroll
        for (int i = 0; i < 6; ++i) pfA[i] = ab[chn[i] * HWSZ];
#pragma unroll
        for (int i = 0; i < 6; ++i) pfD[i] = db[chn[i] * HWSZ];
#pragma unroll
        for (int c = 0; c < 8; ++c) pfC[c] = cb[c * HWSZ];
        pfT = target[b * HWSZ + off];
    }

    const float wbic = 0.2f / (float)(BB * CC * HWSZ);
    const float wcon = 0.8f / (float)(BB * CC * HWSZ);
    const float wpix = 1.0f / (float)(BB * HWSZ);
    const float ln2  = 0.69314718056f;

    float acc = 0.0f;

    for (int r = 0; r < RPB; ++r) {
        // Drains: row-r glds into L[r&1] + row-r register prefetch.
        // Both were issued one full iteration ago (or in the prologue).
        __syncthreads();

        // grab current row's prefetched registers
        float cA[6], cD[6], cC[8];
#pragma unroll
        for (int i = 0; i < 6; ++i) { cA[i] = pfA[i]; cD[i] = pfD[i]; }
#pragma unroll
        for (int c = 0; c < 8; ++c) cC[c] = pfC[c];
        const float cT = pfT;

        const int grow = row0 + r;
        const int h    = grow & (HH - 1);
        const float mh0 = (h > 0) ? 1.0f : 0.0f;
        const float mh1 = (h < HH - 1) ? 1.0f : 0.0f;

        // issue next row's loads: glds -> other buffer, centers -> regs.
        // They fly during this iteration's compute; next barrier drains them.
        if (r + 1 < RPB) {
            const int g2 = grow + 1;
            const int h2 = g2 & (HH - 1);
            const int b2 = g2 >> 9;
            const int hm2 = (h2 > 0) ? h2 - 1 : 0;
            const int hp2 = (h2 < HH - 1) ? h2 + 1 : HH - 1;
            stage_glds(atts + b2 * CHW, dets + b2 * CHW, L[(r + 1) & 1],
                       h2, hm2, hp2, wave, lane);
            const int off2 = h2 * WW + w;
            const float* __restrict__ ab = atts + b2 * CHW + off2;
            const float* __restrict__ db = dets + b2 * CHW + off2;
            const float* __restrict__ cb = con  + b2 * CHW + off2;
            const int chn[6] = {0, 1, 2, 5, 6, 7};
#pragma unroll
            for (int i = 0; i < 6; ++i) pfA[i] = ab[chn[i] * HWSZ];
#pragma unroll
            for (int i = 0; i < 6; ++i) pfD[i] = db[chn[i] * HWSZ];
#pragma unroll
            for (int c = 0; c < 8; ++c) pfC[c] = cb[c * HWSZ];
            pfT = target[b2 * HWSZ + off2];
        }

        // ---------------- compute row r from L[r&1] + registers ----------------
        const float* __restrict__ Lc = L[r & 1];
        float glo1, glo2, vmin2, dum, Lb1, Lc1, Lb2, Lc2;
        eval_branch<false>(Lc,          cA, w, wl, wr, mh0, mh1, mw0, mw1, cC,
                           glo1, dum, Lb1, Lc1);
        eval_branch<true >(Lc + 8 * WW, cD, w, wl, wr, mh0, mh1, mw0, mw1, cC,
                           glo2, vmin2, Lb2, Lc2);

        float csum = 0.f;
#pragma unroll
        for (int c = 0; c < 8; ++c) csum += cC[c];
        const float edge = (csum < 8.0f && csum > 0.0f) ? 1.0f : 0.0f;

        const float dec = (edge > 0.5f) ? (1.0f - vmin2) : glo2;
        const float a   = (cT > 0.5f) ? glo1 : 1.0f - glo1;
        const float bs  = (cT > 0.5f) ? dec  : 1.0f - dec;
        const float Lp  = fmaxf(__log2f(a * bs), LOG2_CLAMP);

        acc += -(wbic * (Lb1 + Lb2) + wcon * (Lc1 + Lc2) + wpix * Lp) * ln2;
    }

    // block reduction, one atomic per block
#pragma unroll
    for (int off = 32; off > 0; off >>= 1)
        acc += __shfl_down(acc, off, 64);
    if (lane == 0) wsum[wave] = acc;
    __syncthreads();
    if (t == 0) {
        float s = 0.f;
#pragma unroll
        for (int i = 0; i < 8; ++i) s += wsum[i];
        atomicAdd(out, s);
    }
}

extern "C" void kernel_launch(void* const* d_in, const int* in_sizes, int n_in,
                              void* d_out, int out_size, void* d_ws, size_t ws_size,
                              hipStream_t stream) {
    const float* atts   = (const float*)d_in[0];
    const float* dets   = (const float*)d_in[1];
    const float* target = (const float*)d_in[2];
    const float* con    = (const float*)d_in[3];
    float* out = (float*)d_out;

    hipMemsetAsync(out, 0, sizeof(float), stream);

    bicon_loss_kernel<<<(BB * HH) / RPB, 512, 0, stream>>>(atts, dets, target, con, out);
}

// Round 7
// 209.675 us; speedup vs baseline: 1.0263x; 1.0263x over previous
//
#include <hip/hip_runtime.h>

#define BB 8
#define CC 8
#define HH 512
#define WW 512
#define HWSZ (HH * WW)
#define CHW (CC * HWSZ)
#define RR 16                      // rows per block (8 b * 32 chunks = 256 blocks)

#define LOG2_CLAMP -144.26950409f  // -100 / ln2

__device__ __forceinline__ float sigf(float x) {
    return __builtin_amdgcn_rcpf(1.0f + __expf(-x));
}

// lgkmcnt(0)-only barrier: synchronizes LDS without draining vmcnt, so global
// prefetch loads stay in flight across it (composable_kernel block_sync_lds
// pattern). 0xC07F = vmcnt 63 | expcnt 7 | lgkmcnt 0.
__device__ __forceinline__ void lds_barrier() {
    __builtin_amdgcn_s_waitcnt(0xC07F);
    __builtin_amdgcn_s_barrier();
}

struct Raw { float a[8]; float d[8]; float c[8]; float t; };

__device__ __forceinline__ void issue_bundle(
    Raw& r,
    const float* const* __restrict__ Ap, const float* const* __restrict__ Dp,
    const float* const* __restrict__ Cp, const float* __restrict__ Tp,
    int grow, int w)
{
    const int off = grow * WW + w;   // coalesced: lane w -> consecutive floats
#pragma unroll
    for (int ch = 0; ch < 8; ++ch) r.a[ch] = Ap[ch][off];
#pragma unroll
    for (int ch = 0; ch < 8; ++ch) r.d[ch] = Dp[ch][off];
#pragma unroll
    for (int ch = 0; ch < 8; ++ch) r.c[ch] = Cp[ch][off];
    r.t = Tp[off];
}

// One branch's votes for row h.
// Lb = 6 LDS rows for this branch in the current buffer:
//   0:ch5@h-1  1:ch7@h-1  2:ch3@h  3:ch4@h  4:ch0@h+1  5:ch2@h+1
// sp/sC/sN = sigmoid register windows for rows h-1 / h / h+1 (8 ch each).
template <bool NEED_MIN>
__device__ __forceinline__ void votes_branch(
    const float* __restrict__ Lb,
    const float* sp, const float* sC, const float* sN, const float* cv,
    int wl, int wr, float mh0, float mh1, float mw0, float mw1,
    float& glo, float& vmin, float& Lbic, float& Lcon)
{
    float n[8];
    n[0] = Lb[1 * WW + wl] * (mh0 * mw0);   // ch7 @ h-1, w-1
    n[1] = sp[6]           *  mh0;          // ch6 @ h-1, w
    n[2] = Lb[0 * WW + wr] * (mh0 * mw1);   // ch5 @ h-1, w+1
    n[3] = Lb[3 * WW + wl] *  mw0;          // ch4 @ h,   w-1
    n[4] = Lb[2 * WW + wr] *  mw1;          // ch3 @ h,   w+1
    n[5] = Lb[5 * WW + wl] * (mh1 * mw0);   // ch2 @ h+1, w-1
    n[6] = sN[1]           *  mh1;          // ch1 @ h+1, w
    n[7] = Lb[4 * WW + wr] * (mh1 * mw1);   // ch0 @ h+1, w+1

    float pb0 = 1.f, pb1 = 1.f, pc = 1.f, vsum = 0.f;
    if (NEED_MIN) vmin = 1e30f;
#pragma unroll
    for (int k = 0; k < 8; ++k) {
        float v = sC[k] * n[k];
        vsum += v;
        if (NEED_MIN) vmin = fminf(vmin, v);
        float t  = cv[k];
        float av = (t > 0.5f) ? v     : 1.0f - v;
        float as = (t > 0.5f) ? sC[k] : 1.0f - sC[k];
        if (k < 4) pb0 *= av; else pb1 *= av;
        pc *= as;
    }
    glo  = vsum * 0.125f;
    Lbic = fmaxf(__log2f(pb0), LOG2_CLAMP) + fmaxf(__log2f(pb1), LOG2_CLAMP);
    Lcon = fmaxf(__log2f(pc), LOG2_CLAMP);
}

__global__ __launch_bounds__(512, 2) void bicon_loss_kernel(
    const float* __restrict__ atts, const float* __restrict__ dets,
    const float* __restrict__ target, const float* __restrict__ con,
    float* __restrict__ out)
{
    __shared__ float Lds[2][12 * WW];   // 48 KB: per buffer 6 rows atts + 6 dets
    __shared__ float wsum[8];

    const int t  = threadIdx.x;         // = column w
    const int w  = t;
    const int b  = blockIdx.x >> 5;     // 32 chunks per batch image
    const int h0 = (blockIdx.x & 31) * RR;

    const int   wl  = (w > 0)      ? w - 1 : 0;
    const int   wr  = (w < WW - 1) ? w + 1 : WW - 1;
    const float mw0 = (w > 0)      ? 1.0f : 0.0f;
    const float mw1 = (w < WW - 1) ? 1.0f : 0.0f;

    // per-channel plane bases (hoist into SGPRs; loads become s-base + v-index)
    const float* Ap[8]; const float* Dp[8]; const float* Cp[8];
#pragma unroll
    for (int ch = 0; ch < 8; ++ch) {
        Ap[ch] = atts + (long)b * CHW + (long)ch * HWSZ;
        Dp[ch] = dets + (long)b * CHW + (long)ch * HWSZ;
        Cp[ch] = con  + (long)b * CHW + (long)ch * HWSZ;
    }
    const float* Tp = target + (long)b * HWSZ;

    // ---- prologue: rows h0-1, h0, h0+1 ----
    Raw r0, r1, r2;
    issue_bundle(r0, Ap, Dp, Cp, Tp, (h0 > 0) ? h0 - 1 : 0, w);
    issue_bundle(r1, Ap, Dp, Cp, Tp, h0, w);
    issue_bundle(r2, Ap, Dp, Cp, Tp, h0 + 1, w);          // h0+1 <= 497 < HH

    float spA[8], spD[8], sCA[8], sCD[8], cvC[8], tgtC;
#pragma unroll
    for (int ch = 0; ch < 8; ++ch) { spA[ch] = sigf(r0.a[ch]); spD[ch] = sigf(r0.d[ch]); }
#pragma unroll
    for (int ch = 0; ch < 8; ++ch) { sCA[ch] = sigf(r1.a[ch]); sCD[ch] = sigf(r1.d[ch]); cvC[ch] = r1.c[ch]; }
    tgtC = r1.t;

    const float wbic = 0.2f / (float)(BB * CC * HWSZ);
    const float wcon = 0.8f / (float)(BB * CC * HWSZ);
    const float wpix = 1.0f / (float)(BB * HWSZ);

    float acc = 0.0f;
    Raw rp = r2;                        // pending raw bundle for row h+1

#pragma unroll 4
    for (int r = 0; r < RR; ++r) {
        const int h = h0 + r;

        // 1. issue prefetch for row h+2 (stays in flight across lds_barrier)
        Raw rnew = rp;
        if (r < RR - 1) {
            const int h2 = (h + 2 < HH) ? h + 2 : HH - 1;
            issue_bundle(rnew, Ap, Dp, Cp, Tp, h2, w);
        }

        // 2. sigmoid row h+1 (each element sigmoided exactly ONCE per launch)
        float sNA[8], sND[8], cvN[8];
#pragma unroll
        for (int ch = 0; ch < 8; ++ch) {
            sNA[ch] = sigf(rp.a[ch]);
            sND[ch] = sigf(rp.d[ch]);
            cvN[ch] = rp.c[ch];
        }
        const float tgtN = rp.t;

        // 3. publish the 12 shifted channels to LDS
        float* __restrict__ Lb = Lds[r & 1];
        Lb[ 0 * WW + w] = spA[5];  Lb[ 1 * WW + w] = spA[7];
        Lb[ 2 * WW + w] = sCA[3];  Lb[ 3 * WW + w] = sCA[4];
        Lb[ 4 * WW + w] = sNA[0];  Lb[ 5 * WW + w] = sNA[2];
        Lb[ 6 * WW + w] = spD[5];  Lb[ 7 * WW + w] = spD[7];
        Lb[ 8 * WW + w] = sCD[3];  Lb[ 9 * WW + w] = sCD[4];
        Lb[10 * WW + w] = sND[0];  Lb[11 * WW + w] = sND[2];

        // 4. LDS-only barrier (global prefetch keeps flying)
        lds_barrier();

        // 5. votes + BCE for row h
        const float mh0 = (h > 0)      ? 1.0f : 0.0f;
        const float mh1 = (h < HH - 1) ? 1.0f : 0.0f;

        float glo1, glo2, vmin2, dum, Lb1, Lc1, Lb2, Lc2;
        votes_branch<false>(Lb,          spA, sCA, sNA, cvC, wl, wr,
                            mh0, mh1, mw0, mw1, glo1, dum, Lb1, Lc1);
        votes_branch<true >(Lb + 6 * WW, spD, sCD, sND, cvC, wl, wr,
                            mh0, mh1, mw0, mw1, glo2, vmin2, Lb2, Lc2);

        float csum = 0.f;
#pragma unroll
        for (int ch = 0; ch < 8; ++ch) csum += cvC[ch];
        const float edge = (csum < 8.0f && csum > 0.0f) ? 1.0f : 0.0f;

        const float dec = (edge > 0.5f) ? (1.0f - vmin2) : glo2;
        const float pa  = (tgtC > 0.5f) ? glo1 : 1.0f - glo1;
        const float pb  = (tgtC > 0.5f) ? dec  : 1.0f - dec;
        const float Lp  = fmaxf(__log2f(pa * pb), LOG2_CLAMP);

        acc += wbic * (Lb1 + Lb2) + wcon * (Lc1 + Lc2) + wpix * Lp;

        // 6. rotate windows (pure SSA renames after unrolling)
#pragma unroll
        for (int ch = 0; ch < 8; ++ch) {
            spA[ch] = sCA[ch];  spD[ch] = sCD[ch];
            sCA[ch] = sNA[ch];  sCD[ch] = sND[ch];
            cvC[ch] = cvN[ch];
        }
        tgtC = tgtN;
        rp = rnew;
    }

    acc *= -0.69314718056f;             // * ln2, negate (BCE sign)

    // block reduction, one atomic per block
#pragma unroll
    for (int off = 32; off > 0; off >>= 1)
        acc += __shfl_down(acc, off, 64);
    const int lane = t & 63;
    const int wid  = t >> 6;
    if (lane == 0) wsum[wid] = acc;
    __syncthreads();
    if (t == 0) {
        float s = 0.f;
#pragma unroll
        for (int i = 0; i < 8; ++i) s += wsum[i];
        atomicAdd(out, s);
    }
}

extern "C" void kernel_launch(void* const* d_in, const int* in_sizes, int n_in,
                              void* d_out, int out_size, void* d_ws, size_t ws_size,
                              hipStream_t stream) {
    const float* atts   = (const float*)d_in[0];
    const float* dets   = (const float*)d_in[1];
    const float* target = (const float*)d_in[2];
    const float* con    = (const float*)d_in[3];
    float* out = (float*)d_out;

    hipMemsetAsync(out, 0, sizeof(float), stream);

    bicon_loss_kernel<<<BB * (HH / RR), 512, 0, stream>>>(atts, dets, target, con, out);
}

// Round 8
// 203.822 us; speedup vs baseline: 1.0558x; 1.0287x over previous
//
#include <hip/hip_runtime.h>

#define BB 8
#define CC 8
#define HH 512
#define WW 512
#define HWSZ (HH * WW)
#define CHW (CC * HWSZ)

typedef float v4 __attribute__((ext_vector_type(4)));

#define LOG2_CLAMP -144.26950409f   // -100 / ln2

__device__ __forceinline__ float sigf(float x) {
    return __builtin_amdgcn_rcpf(1.0f + __expf(-x));
}
__device__ __forceinline__ v4 aload4(const float* __restrict__ p) {
    return *(const v4* __restrict__)p;
}
__device__ __forceinline__ v4 sig4(v4 x) {
    v4 r;
#pragma unroll
    for (int i = 0; i < 4; ++i) r[i] = sigf(x[i]);
    return r;
}
__device__ __forceinline__ v4 vsel(v4 t, v4 a, v4 b) {
    v4 r;
#pragma unroll
    for (int i = 0; i < 4; ++i) r[i] = (t[i] > 0.5f) ? a[i] : b[i];
    return r;
}

// values at w-1 for a v4 covering w0..w0+3: {lane-1.s3, s0, s1, s2}
__device__ __forceinline__ v4 mk_left(v4 s, float e, int lane) {
    float y = __shfl_up(s[3], 1, 64);
    y = (lane == 0) ? e : y;          // cross-wave / image-edge fixup
    v4 r = {y, s[0], s[1], s[2]};
    return r;
}
// values at w+1: {s1, s2, s3, lane+1.s0}
__device__ __forceinline__ v4 mk_right(v4 s, float e, int lane) {
    float x = __shfl_down(s[0], 1, 64);
    x = (lane == 63) ? e : x;
    v4 r = {s[1], s[2], s[3], x};
    return r;
}

// One branch. 14 aligned v4 loads: centers ch0..7 @ h, ch5,6,7 @ hm, ch0,1,2 @ hp.
// All w-shifts built from post-sigmoid registers via shuffles (eL/eR = 3 edge
// fixup values each, valid on lane 0 / lane 63 only).
template <bool NEED_MIN>
__device__ __forceinline__ void eval_branch(
    const float* __restrict__ base, int oC, int oU, int oD,
    float mh0, float mh1, v4 mwL, v4 mwR,
    const v4* __restrict__ cv, const float* eL, const float* eR, int lane,
    v4& glo, v4& vmin, float& Lbic, float& Lcon)
{
    v4 s[8];
#pragma unroll
    for (int c = 0; c < 8; ++c) s[c] = sig4(aload4(base + c * HWSZ + oC));
    v4 s5m = sig4(aload4(base + 5 * HWSZ + oU));
    v4 s6m = sig4(aload4(base + 6 * HWSZ + oU));
    v4 s7m = sig4(aload4(base + 7 * HWSZ + oU));
    v4 s0p = sig4(aload4(base + 0 * HWSZ + oD));
    v4 s1p = sig4(aload4(base + 1 * HWSZ + oD));
    v4 s2p = sig4(aload4(base + 2 * HWSZ + oD));

    v4 n[8];
    n[0] = mk_left (s7m,  eL[1], lane) * (mh0 * mwL);   // ch7 @ h-1, w-1
    n[1] = s6m * mh0;                                   // ch6 @ h-1, w
    n[2] = mk_right(s5m,  eR[1], lane) * (mh0 * mwR);   // ch5 @ h-1, w+1
    n[3] = mk_left (s[4], eL[0], lane) * mwL;           // ch4 @ h,   w-1
    n[4] = mk_right(s[3], eR[0], lane) * mwR;           // ch3 @ h,   w+1
    n[5] = mk_left (s2p,  eL[2], lane) * (mh1 * mwL);   // ch2 @ h+1, w-1
    n[6] = s1p * mh1;                                   // ch1 @ h+1, w
    n[7] = mk_right(s0p,  eR[2], lane) * (mh1 * mwR);   // ch0 @ h+1, w+1

    v4 one = {1.f, 1.f, 1.f, 1.f};
    v4 pb0 = one, pb1 = one, pc = one, vsum = {0.f, 0.f, 0.f, 0.f};
    if (NEED_MIN) vmin = {1e30f, 1e30f, 1e30f, 1e30f};
#pragma unroll
    for (int k = 0; k < 8; ++k) {
        v4 v = s[k] * n[k];
        vsum += v;
        if (NEED_MIN) vmin = __builtin_elementwise_min(vmin, v);
        v4 t  = cv[k];
        v4 av = vsel(t, v, one - v);
        v4 as = vsel(t, s[k], one - s[k]);
        if (k < 4) pb0 *= av; else pb1 *= av;
        pc *= as;
    }
    glo = vsum * 0.125f;

    float lb = 0.f, lc = 0.f;
#pragma unroll
    for (int i = 0; i < 4; ++i) {
        lb += fmaxf(__log2f(pb0[i]), LOG2_CLAMP) + fmaxf(__log2f(pb1[i]), LOG2_CLAMP);
        lc += fmaxf(__log2f(pc[i]), LOG2_CLAMP);
    }
    Lbic = lb;
    Lcon = lc;
}

__global__ __launch_bounds__(256) void bicon_loss_kernel(
    const float* __restrict__ atts, const float* __restrict__ dets,
    const float* __restrict__ target, const float* __restrict__ con,
    float* __restrict__ out)
{
    const int idx = blockIdx.x * 256 + threadIdx.x;  // 4-px group id
    const int w0  = (idx & 127) << 2;
    const int row = idx >> 7;                        // b*H + h (wave-uniform)
    const int h   = row & (HH - 1);
    const int b   = row >> 9;
    const int lane = threadIdx.x & 63;

    const int hm = (h > 0) ? h - 1 : 0;
    const int hp = (h < HH - 1) ? h + 1 : HH - 1;
    const float mh0 = (h > 0) ? 1.0f : 0.0f;
    const float mh1 = (h < HH - 1) ? 1.0f : 0.0f;
    const v4 mwL = {(w0 == 0) ? 0.0f : 1.0f, 1.f, 1.f, 1.f};
    const v4 mwR = {1.f, 1.f, 1.f, (w0 == WW - 4) ? 0.0f : 1.0f};

    const int oC = h * WW + w0;
    const int oU = hm * WW + w0;
    const int oD = hp * WW + w0;

    const float* __restrict__ ab = atts + b * CHW;
    const float* __restrict__ db = dets + b * CHW;
    const float* __restrict__ cb = con  + b * CHW;

    // con channels + target + edge mask
    v4 cv[8];
    v4 csum = {0.f, 0.f, 0.f, 0.f};
#pragma unroll
    for (int c = 0; c < 8; ++c) {
        cv[c] = aload4(cb + c * HWSZ + oC);
        csum += cv[c];
    }
    v4 edge;
#pragma unroll
    for (int i = 0; i < 4; ++i)
        edge[i] = (csum[i] < 8.0f && csum[i] > 0.0f) ? 1.0f : 0.0f;
    const v4 t4 = aload4(target + b * HWSZ + oC);

    // edge fixups: lane 0 needs w0-1 values (left-shift), lane 63 needs w0+4
    // (right-shift). Clamped addresses; image-edge cases are masked by mwL/mwR.
    float eLA[3] = {0.f, 0.f, 0.f}, eRA[3] = {0.f, 0.f, 0.f};
    float eLD[3] = {0.f, 0.f, 0.f}, eRD[3] = {0.f, 0.f, 0.f};
    if (lane == 0) {
        const int wl = (w0 > 0) ? w0 - 1 : 0;
        eLA[0] = sigf(ab[4 * HWSZ + h  * WW + wl]);
        eLA[1] = sigf(ab[7 * HWSZ + hm * WW + wl]);
        eLA[2] = sigf(ab[2 * HWSZ + hp * WW + wl]);
        eLD[0] = sigf(db[4 * HWSZ + h  * WW + wl]);
        eLD[1] = sigf(db[7 * HWSZ + hm * WW + wl]);
        eLD[2] = sigf(db[2 * HWSZ + hp * WW + wl]);
    }
    if (lane == 63) {
        const int w2 = (w0 + 4 < WW) ? w0 + 4 : WW - 1;
        eRA[0] = sigf(ab[3 * HWSZ + h  * WW + w2]);
        eRA[1] = sigf(ab[5 * HWSZ + hm * WW + w2]);
        eRA[2] = sigf(ab[0 * HWSZ + hp * WW + w2]);
        eRD[0] = sigf(db[3 * HWSZ + h  * WW + w2]);
        eRD[1] = sigf(db[5 * HWSZ + hm * WW + w2]);
        eRD[2] = sigf(db[0 * HWSZ + hp * WW + w2]);
    }

    v4 glo1, glo2, vmin2, dum;
    float Lb1, Lc1, Lb2, Lc2;
    eval_branch<false>(ab, oC, oU, oD, mh0, mh1, mwL, mwR, cv, eLA, eRA, lane,
                       glo1, dum, Lb1, Lc1);
    eval_branch<true >(db, oC, oU, oD, mh0, mh1, mwL, mwR, cv, eLD, eRD, lane,
                       glo2, vmin2, Lb2, Lc2);

    // pixel-level BCE pair, one log
    float Lp = 0.f;
#pragma unroll
    for (int i = 0; i < 4; ++i) {
        float dec = (edge[i] > 0.5f) ? (1.0f - vmin2[i]) : glo2[i];
        float a   = (t4[i] > 0.5f) ? glo1[i] : 1.0f - glo1[i];
        float bs  = (t4[i] > 0.5f) ? dec     : 1.0f - dec;
        Lp += fmaxf(__log2f(a * bs), LOG2_CLAMP);
    }

    const float wbic = 0.2f / (float)(BB * CC * HWSZ);
    const float wcon = 0.8f / (float)(BB * CC * HWSZ);
    const float wpix = 1.0f / (float)(BB * HWSZ);
    const float ln2  = 0.69314718056f;

    float local = -(wbic * (Lb1 + Lb2) + wcon * (Lc1 + Lc2) + wpix * Lp) * ln2;

#pragma unroll
    for (int off = 32; off > 0; off >>= 1)
        local += __shfl_down(local, off, 64);

    __shared__ float wsum[4];
    const int wid = threadIdx.x >> 6;
    if (lane == 0) wsum[wid] = local;
    __syncthreads();
    if (threadIdx.x == 0) {
        float s = wsum[0] + wsum[1] + wsum[2] + wsum[3];
        atomicAdd(out, s);
    }
}

extern "C" void kernel_launch(void* const* d_in, const int* in_sizes, int n_in,
                              void* d_out, int out_size, void* d_ws, size_t ws_size,
                              hipStream_t stream) {
    const float* atts   = (const float*)d_in[0];
    const float* dets   = (const float*)d_in[1];
    const float* target = (const float*)d_in[2];
    const float* con    = (const float*)d_in[3];
    float* out = (float*)d_out;

    hipMemsetAsync(out, 0, sizeof(float), stream);

    const int ngroups = BB * HH * WW / 4;   // 524288 threads, 4 px each
    bicon_loss_kernel<<<ngroups / 256, 256, 0, stream>>>(atts, dets, target, con, out);
}